// Round 1
// baseline (11888.757 us; speedup 1.0000x reference)
//
#include <hip/hip_runtime.h>

// GNODE: y' = f(y) = relu(y@W1+b1)@W2+b2, RK4(3/8-rule) x 10 steps, h=0.1,
// then out = y@Wl+bl.  N=200000 rows, 128 channels, 64 out channels.
//
// Round 1: fp32 VALU baseline (no fp32 MFMA on CDNA4).
// - feval_kernel fuses: arg-build (RK4 linear combo) -> matmul1+relu ->
//   matmul2 -> RK4 combine/writeback.  41 launches total.
// - State buffers in d_ws: Y, A, B (each N*128 f32 = 102.4MB; total 307MB).
//   RK4 3/8 with 3 buffers: A<-k1; B<-k2; E3: A<-k1+3k2+3k3, B<-k1-k2+k3;
//   E4: Y <- Y + h/8*(A + k4).
// - LDS: W (64KB, k-major) + activations transposed k-major with +4 pad
//   (conflict-free b128 reads on activation side; W reads 4-way, accepted).

constexpr int TM = 128;          // rows per block tile
constexpr float H = 0.1f;

__device__ __forceinline__ float4 f4_axpy(float s, float4 a, float4 acc) {
    acc.x = fmaf(s, a.x, acc.x);
    acc.y = fmaf(s, a.y, acc.y);
    acc.z = fmaf(s, a.z, acc.z);
    acc.w = fmaf(s, a.w, acc.w);
    return acc;
}

__global__ __launch_bounds__(256) void feval_kernel(
    const float* __restrict__ Yin, float* __restrict__ Yout,
    float* __restrict__ A, float* __restrict__ B,
    const float* __restrict__ W1, const float* __restrict__ b1,
    const float* __restrict__ W2, const float* __restrict__ b2,
    int n, int mode)
{
    __shared__ float sW[128 * 128];      // weights, k-major: sW[k*128+c]
    __shared__ float sIO[128 * 132];     // activations transposed: sIO[k*132+r]
    __shared__ float sBias[128];

    const int tid  = threadIdx.x;
    const int row0 = blockIdx.x * TM;

    // ---- stage W1 + b1 into LDS (coalesced float4)
    {
        const float4* w4 = (const float4*)W1;
        float4* s4 = (float4*)sW;
        #pragma unroll
        for (int i = 0; i < 16; ++i) s4[tid + i * 256] = w4[tid + i * 256];
        if (tid < 128) sBias[tid] = b1[tid];
    }

    // ---- build arg tile, store transposed into sIO[k][r]
    {
        const float4* Y4 = (const float4*)Yin;
        const float4* A4 = (const float4*)A;
        const float4* B4 = (const float4*)B;
        #pragma unroll
        for (int i = 0; i < 16; ++i) {
            int f  = tid + i * 256;      // float4 index within tile (0..4095)
            int r  = f >> 5;             // tile row (0..127)
            int k4 = f & 31;             // float4 index along k
            float4 v;
            int gr = row0 + r;
            if (gr < n) {
                int g = gr * 32 + k4;
                v = Y4[g];
                if (mode == 2) {                       // y + (h/3) k1
                    v = f4_axpy(H / 3.f, A4[g], v);
                } else if (mode == 3) {                // y + h k2 - (h/3) k1
                    v = f4_axpy(H, B4[g], v);
                    v = f4_axpy(-H / 3.f, A4[g], v);
                } else if (mode == 4) {                // y + h (k1 - k2 + k3)
                    v = f4_axpy(H, B4[g], v);
                }
            } else {
                v = make_float4(0.f, 0.f, 0.f, 0.f);
            }
            int k = k4 * 4;
            sIO[(k + 0) * 132 + r] = v.x;
            sIO[(k + 1) * 132 + r] = v.y;
            sIO[(k + 2) * 132 + r] = v.z;
            sIO[(k + 3) * 132 + r] = v.w;
        }
    }
    __syncthreads();

    const int tx = tid & 15;     // col group: cols tx*8 .. tx*8+7
    const int ty = tid >> 4;     // row group: rows ty*8 .. ty*8+7

    // ---- matmul1: h = relu(arg @ W1 + b1)
    float acc[8][8];
    #pragma unroll
    for (int j = 0; j < 8; ++j)
        #pragma unroll
        for (int i = 0; i < 8; ++i) acc[j][i] = sBias[tx * 8 + i];

    #pragma unroll 4
    for (int k = 0; k < 128; ++k) {
        float a[8], w[8];
        *(float4*)&a[0] = *(const float4*)&sIO[k * 132 + ty * 8];
        *(float4*)&a[4] = *(const float4*)&sIO[k * 132 + ty * 8 + 4];
        *(float4*)&w[0] = *(const float4*)&sW[k * 128 + tx * 8];
        *(float4*)&w[4] = *(const float4*)&sW[k * 128 + tx * 8 + 4];
        #pragma unroll
        for (int j = 0; j < 8; ++j)
            #pragma unroll
            for (int i = 0; i < 8; ++i)
                acc[j][i] = fmaf(a[j], w[i], acc[j][i]);
    }
    __syncthreads();   // all reads of sIO/sW/sBias done

    // ---- stage W2 + b2; write h (relu) transposed into sIO[c][r]
    {
        const float4* w4 = (const float4*)W2;
        float4* s4 = (float4*)sW;
        #pragma unroll
        for (int i = 0; i < 16; ++i) s4[tid + i * 256] = w4[tid + i * 256];
        if (tid < 128) sBias[tid] = b2[tid];
    }
    #pragma unroll
    for (int j = 0; j < 8; ++j)
        #pragma unroll
        for (int i = 0; i < 8; ++i)
            sIO[(tx * 8 + i) * 132 + (ty * 8 + j)] = fmaxf(acc[j][i], 0.f);
    __syncthreads();

    // ---- matmul2: k = h @ W2 + b2
    float acc2[8][8];
    #pragma unroll
    for (int j = 0; j < 8; ++j)
        #pragma unroll
        for (int i = 0; i < 8; ++i) acc2[j][i] = sBias[tx * 8 + i];

    #pragma unroll 4
    for (int k = 0; k < 128; ++k) {
        float a[8], w[8];
        *(float4*)&a[0] = *(const float4*)&sIO[k * 132 + ty * 8];
        *(float4*)&a[4] = *(const float4*)&sIO[k * 132 + ty * 8 + 4];
        *(float4*)&w[0] = *(const float4*)&sW[k * 128 + tx * 8];
        *(float4*)&w[4] = *(const float4*)&sW[k * 128 + tx * 8 + 4];
        #pragma unroll
        for (int j = 0; j < 8; ++j)
            #pragma unroll
            for (int i = 0; i < 8; ++i)
                acc2[j][i] = fmaf(a[j], w[i], acc2[j][i]);
    }

    // ---- writeback per mode (float4 along columns)
    {
        float4* A4 = (float4*)A;
        float4* B4 = (float4*)B;
        const float4* Y4 = (const float4*)Yin;
        float4* Yo4 = (float4*)Yout;
        #pragma unroll
        for (int j = 0; j < 8; ++j) {
            int gr = row0 + ty * 8 + j;
            if (gr >= n) continue;
            #pragma unroll
            for (int hh = 0; hh < 2; ++hh) {
                float4 kv = make_float4(acc2[j][hh * 4 + 0], acc2[j][hh * 4 + 1],
                                        acc2[j][hh * 4 + 2], acc2[j][hh * 4 + 3]);
                int g = gr * 32 + tx * 2 + hh;
                if (mode == 1) {
                    A4[g] = kv;                            // A <- k1
                } else if (mode == 2) {
                    B4[g] = kv;                            // B <- k2
                } else if (mode == 3) {
                    float4 a = A4[g], b = B4[g];
                    float4 na, nb;
                    na.x = a.x + 3.f * b.x + 3.f * kv.x;   // A <- k1+3k2+3k3
                    na.y = a.y + 3.f * b.y + 3.f * kv.y;
                    na.z = a.z + 3.f * b.z + 3.f * kv.z;
                    na.w = a.w + 3.f * b.w + 3.f * kv.w;
                    nb.x = a.x - b.x + kv.x;               // B <- k1-k2+k3
                    nb.y = a.y - b.y + kv.y;
                    nb.z = a.z - b.z + kv.z;
                    nb.w = a.w - b.w + kv.w;
                    A4[g] = na;
                    B4[g] = nb;
                } else {
                    float4 y = Y4[g], ap = A4[g];
                    y.x = fmaf(H / 8.f, ap.x + kv.x, y.x); // Y <- Y + h/8(A+k4)
                    y.y = fmaf(H / 8.f, ap.y + kv.y, y.y);
                    y.z = fmaf(H / 8.f, ap.z + kv.z, y.z);
                    y.w = fmaf(H / 8.f, ap.w + kv.w, y.w);
                    Yo4[g] = y;
                }
            }
        }
    }
}

// out = Y @ Wl + bl   (128 -> 64)
__global__ __launch_bounds__(256) void final_kernel(
    const float* __restrict__ Y, const float* __restrict__ Wl,
    const float* __restrict__ bl, float* __restrict__ out, int n)
{
    __shared__ float sW[128 * 64];
    __shared__ float sIO[128 * 132];
    __shared__ float sBias[64];

    const int tid  = threadIdx.x;
    const int row0 = blockIdx.x * TM;

    {
        const float4* w4 = (const float4*)Wl;
        float4* s4 = (float4*)sW;
        #pragma unroll
        for (int i = 0; i < 8; ++i) s4[tid + i * 256] = w4[tid + i * 256];
        if (tid < 64) sBias[tid] = bl[tid];
    }
    {
        const float4* Y4 = (const float4*)Y;
        #pragma unroll
        for (int i = 0; i < 16; ++i) {
            int f  = tid + i * 256;
            int r  = f >> 5;
            int k4 = f & 31;
            float4 v;
            int gr = row0 + r;
            if (gr < n) v = Y4[gr * 32 + k4];
            else        v = make_float4(0.f, 0.f, 0.f, 0.f);
            int k = k4 * 4;
            sIO[(k + 0) * 132 + r] = v.x;
            sIO[(k + 1) * 132 + r] = v.y;
            sIO[(k + 2) * 132 + r] = v.z;
            sIO[(k + 3) * 132 + r] = v.w;
        }
    }
    __syncthreads();

    const int tx = tid & 15;   // cols tx*4 .. +3 (of 64)
    const int ty = tid >> 4;   // rows ty*8 .. +7

    float acc[8][4];
    #pragma unroll
    for (int j = 0; j < 8; ++j)
        #pragma unroll
        for (int i = 0; i < 4; ++i) acc[j][i] = sBias[tx * 4 + i];

    #pragma unroll 4
    for (int k = 0; k < 128; ++k) {
        float a[8], w[4];
        *(float4*)&a[0] = *(const float4*)&sIO[k * 132 + ty * 8];
        *(float4*)&a[4] = *(const float4*)&sIO[k * 132 + ty * 8 + 4];
        *(float4*)&w[0] = *(const float4*)&sW[k * 64 + tx * 4];
        #pragma unroll
        for (int j = 0; j < 8; ++j)
            #pragma unroll
            for (int i = 0; i < 4; ++i)
                acc[j][i] = fmaf(a[j], w[i], acc[j][i]);
    }

    #pragma unroll
    for (int j = 0; j < 8; ++j) {
        int gr = row0 + ty * 8 + j;
        if (gr >= n) continue;
        ((float4*)out)[gr * 16 + tx] =
            make_float4(acc[j][0], acc[j][1], acc[j][2], acc[j][3]);
    }
}

extern "C" void kernel_launch(void* const* d_in, const int* in_sizes, int n_in,
                              void* d_out, int out_size, void* d_ws, size_t ws_size,
                              hipStream_t stream)
{
    const float* x  = (const float*)d_in[0];
    const float* W1 = (const float*)d_in[1];
    const float* b1 = (const float*)d_in[2];
    const float* W2 = (const float*)d_in[3];
    const float* b2 = (const float*)d_in[4];
    const float* Wl = (const float*)d_in[5];
    const float* bl = (const float*)d_in[6];
    float* out = (float*)d_out;

    const int n = in_sizes[0] / 128;
    const size_t SZ = (size_t)n * 128;     // floats per state buffer

    // ws layout: Y | A | B  (needs 3*SZ*4 = ~307MB)
    float* Yw = (float*)d_ws;
    float* A  = Yw + SZ;
    float* B  = A + SZ;

    const int nb = (n + TM - 1) / TM;
    dim3 grid(nb), block(256);

    for (int s = 0; s < 10; ++s) {
        const float* Yin = (s == 0) ? x : Yw;
        feval_kernel<<<grid, block, 0, stream>>>(Yin, Yw, A, B, W1, b1, W2, b2, n, 1);
        feval_kernel<<<grid, block, 0, stream>>>(Yin, Yw, A, B, W1, b1, W2, b2, n, 2);
        feval_kernel<<<grid, block, 0, stream>>>(Yin, Yw, A, B, W1, b1, W2, b2, n, 3);
        feval_kernel<<<grid, block, 0, stream>>>(Yin, Yw, A, B, W1, b1, W2, b2, n, 4);
    }
    final_kernel<<<grid, block, 0, stream>>>(Yw, Wl, bl, out, n);
}

// Round 2
// 774.324 us; speedup vs baseline: 15.3537x; 15.3537x over previous
//
#include <hip/hip_runtime.h>

// GNODE fully fused: y' = relu(y@W1+b1)@W2+b2, RK4(3/8) x10 steps (h=0.1),
// out = y@Wl+bl.  N=200000 rows, 128 ch, 64 out ch.
//
// Round 2: single mega-kernel, bf16 MFMA, zero LDS / zero barriers.
// Transposed dataflow: k^T = W^T(A-operand, static frags in VGPRs) @ arg^T
// (B-operand, built lane-locally from state).  Key identity for
// mfma_f32_16x16x32_bf16:
//   D-layout:   ch = 16*cb + 4*(lane>>4) + r,             batch = lane&15
//   B-frag:     ch = 32*kb + 16*(j>>2) + 4*(lane>>4)+(j&3), batch = lane&15
// => bfrag[kb][j] = state[8*kb + j]  (pure lane-local register rearrange).
// Wave owns 16 batch rows x 128 ch: 32 f32 state elems/lane.
// W1,W2 A-frags: 32 frags x 4 VGPR x 2 = 256 VGPRs  -> 1 wave/SIMD (by design).
// Prep kernel builds A-frag-linear weights + packed-bf16 biases in d_ws.

typedef __attribute__((ext_vector_type(8))) short bf16x8;
typedef __attribute__((ext_vector_type(4))) float f32x4;

constexpr float HS = 0.1f;

__device__ __forceinline__ unsigned short bf16r(float f) {
    unsigned u = __builtin_bit_cast(unsigned, f);
    u += 0x7fffu + ((u >> 16) & 1u);          // RNE (finite data, no NaN)
    return (unsigned short)(u >> 16);
}
__device__ __forceinline__ float bplo(unsigned u) { return __builtin_bit_cast(float, u << 16); }
__device__ __forceinline__ float bphi(unsigned u) { return __builtin_bit_cast(float, u & 0xffff0000u); }

// dst = (relu?)(W @ src + b): one 128x128 matmul, all operands lane-local.
template<bool RELU>
__device__ __forceinline__ void mm128(const bf16x8 (&wf)[32], const unsigned (&bp)[16],
                                      const float (&src)[32], float (&dst)[32])
{
    bf16x8 bf[4];
    #pragma unroll
    for (int kb = 0; kb < 4; ++kb)
        #pragma unroll
        for (int j = 0; j < 8; ++j)
            bf[kb][j] = (short)bf16r(src[kb * 8 + j]);

    f32x4 acc[8];
    #pragma unroll
    for (int mb = 0; mb < 8; ++mb) {
        acc[mb][0] = bplo(bp[mb * 2 + 0]);
        acc[mb][1] = bphi(bp[mb * 2 + 0]);
        acc[mb][2] = bplo(bp[mb * 2 + 1]);
        acc[mb][3] = bphi(bp[mb * 2 + 1]);
    }
    #pragma unroll
    for (int kb = 0; kb < 4; ++kb)              // inner mb: 8 independent accs
        #pragma unroll
        for (int mb = 0; mb < 8; ++mb)
            acc[mb] = __builtin_amdgcn_mfma_f32_16x16x32_bf16(wf[mb * 4 + kb], bf[kb], acc[mb], 0, 0, 0);
    #pragma unroll
    for (int mb = 0; mb < 8; ++mb)
        #pragma unroll
        for (int r = 0; r < 4; ++r)
            dst[mb * 4 + r] = RELU ? fmaxf(acc[mb][r], 0.f) : acc[mb][r];
}

__device__ __forceinline__ void feval(const bf16x8 (&w1f)[32], const bf16x8 (&w2f)[32],
                                      const unsigned (&b1p)[16], const unsigned (&b2p)[16],
                                      const float (&arg)[32], float (&kout)[32])
{
    float h[32];
    mm128<true >(w1f, b1p, arg, h);
    mm128<false>(w2f, b2p, h, kout);
}

__global__ __launch_bounds__(256, 1) void gnode_kernel(
    const float* __restrict__ x, const uint4* __restrict__ wfr,
    const unsigned* __restrict__ b1pg, const unsigned* __restrict__ b2pg,
    const float* __restrict__ bl, float* __restrict__ out, int n)
{
    const int lane = threadIdx.x & 63;
    const int wid  = threadIdx.x >> 6;
    const int g    = lane >> 4;
    const int c16  = lane & 15;
    const int row  = blockIdx.x * 64 + wid * 16 + c16;   // this lane's batch row
    const int rowc = row < n ? row : n - 1;

    bf16x8 w1f[32], w2f[32];
    #pragma unroll
    for (int f = 0; f < 32; ++f) w1f[f] = __builtin_bit_cast(bf16x8, wfr[f * 64 + lane]);
    #pragma unroll
    for (int f = 0; f < 32; ++f) w2f[f] = __builtin_bit_cast(bf16x8, wfr[(32 + f) * 64 + lane]);

    unsigned b1p[16], b2p[16];
    #pragma unroll
    for (int p = 0; p < 16; ++p) b1p[p] = b1pg[lane * 16 + p];
    #pragma unroll
    for (int p = 0; p < 16; ++p) b2p[p] = b2pg[lane * 16 + p];

    // Y^T state, fp32 master: elem e=4*cb+r <-> (ch = 16*cb+4*g+r, batch=row)
    float y[32];
    {
        const f32x4* x4 = (const f32x4*)x;
        #pragma unroll
        for (int cb = 0; cb < 8; ++cb) {
            f32x4 v = x4[(size_t)rowc * 32 + cb * 4 + g];
            y[cb * 4 + 0] = v[0]; y[cb * 4 + 1] = v[1];
            y[cb * 4 + 2] = v[2]; y[cb * 4 + 3] = v[3];
        }
    }

    float ka[32], kb[32], s[32], arg[32];

    for (int st = 0; st < 10; ++st) {
        // k1
        feval(w1f, w2f, b1p, b2p, y, ka);
        // arg2 = y + (h/3) k1
        #pragma unroll
        for (int e = 0; e < 32; ++e) arg[e] = fmaf(HS * (1.f / 3.f), ka[e], y[e]);
        feval(w1f, w2f, b1p, b2p, arg, kb);                       // k2
        // arg3 = y + h k2 - (h/3) k1
        #pragma unroll
        for (int e = 0; e < 32; ++e)
            arg[e] = fmaf(HS, kb[e], fmaf(-HS * (1.f / 3.f), ka[e], y[e]));
        feval(w1f, w2f, b1p, b2p, arg, s);                        // k3
        // fold: ka <- k1+3k2+3k3 ; kb <- k1-k2+k3
        #pragma unroll
        for (int e = 0; e < 32; ++e) {
            float u = kb[e];
            kb[e] = ka[e] - u + s[e];
            ka[e] = fmaf(3.f, u + s[e], ka[e]);
        }
        // arg4 = y + h (k1-k2+k3)
        #pragma unroll
        for (int e = 0; e < 32; ++e) arg[e] = fmaf(HS, kb[e], y[e]);
        feval(w1f, w2f, b1p, b2p, arg, s);                        // k4
        // y += h/8 (ka + k4)
        #pragma unroll
        for (int e = 0; e < 32; ++e) y[e] = fmaf(HS * 0.125f, ka[e] + s[e], y[e]);
    }

    // epilogue: out^T = Wl^T y^T + bl   (64 out ch = 4 mb)
    bf16x8 wlf[16];
    #pragma unroll
    for (int f = 0; f < 16; ++f) wlf[f] = __builtin_bit_cast(bf16x8, wfr[(64 + f) * 64 + lane]);
    bf16x8 yf[4];
    #pragma unroll
    for (int kv = 0; kv < 4; ++kv)
        #pragma unroll
        for (int j = 0; j < 8; ++j) yf[kv][j] = (short)bf16r(y[kv * 8 + j]);
    f32x4 ao[4];
    {
        const f32x4* bl4 = (const f32x4*)bl;
        #pragma unroll
        for (int mb = 0; mb < 4; ++mb) ao[mb] = bl4[mb * 4 + g];   // bl[16mb+4g+r]
    }
    #pragma unroll
    for (int kv = 0; kv < 4; ++kv)
        #pragma unroll
        for (int mb = 0; mb < 4; ++mb)
            ao[mb] = __builtin_amdgcn_mfma_f32_16x16x32_bf16(wlf[mb * 4 + kv], yf[kv], ao[mb], 0, 0, 0);
    if (row < n) {
        f32x4* out4 = (f32x4*)out;
        #pragma unroll
        for (int mb = 0; mb < 4; ++mb)
            out4[(size_t)row * 16 + mb * 4 + g] = ao[mb];          // out[row][16mb+4g+r]
    }
}

// ---- prep: A-frag-linear bf16 weights + packed-bf16 biases into d_ws ----
// A-frag (16x32): lane l, elem j:  row = l&15 (+16*mb),
//                                  k   = 32*kb + 16*(j>>2) + 4*(l>>4) + (j&3)
// wfr[f*64+lane] : f 0..31 = W1 (mb=f>>2,kb=f&3), 32..63 = W2, 64..79 = Wl.
__global__ void prep_kernel(const float* __restrict__ W1, const float* __restrict__ W2,
                            const float* __restrict__ Wl,
                            const float* __restrict__ b1, const float* __restrict__ b2,
                            uint4* __restrict__ wfr, unsigned* __restrict__ b1p,
                            unsigned* __restrict__ b2p)
{
    int t = blockIdx.x * 256 + threadIdx.x;
    if (t < 80 * 64) {
        int f = t >> 6, lane = t & 63;
        int gq = lane >> 4, c = lane & 15;
        const float* W; int mb, kv, cols;
        if (f < 32)      { W = W1; mb = f >> 2;        kv = f & 3;        cols = 128; }
        else if (f < 64) { W = W2; mb = (f - 32) >> 2; kv = (f - 32) & 3; cols = 128; }
        else             { W = Wl; mb = (f - 64) >> 2; kv = (f - 64) & 3; cols = 64;  }
        int col = mb * 16 + c;               // output-channel (A row)
        unsigned short v[8];
        #pragma unroll
        for (int j = 0; j < 8; ++j) {
            int k = kv * 32 + (j >> 2) * 16 + gq * 4 + (j & 3);
            v[j] = bf16r(W[k * cols + col]); // W[k][c] row-major
        }
        uint4 o;
        o.x = (unsigned)v[0] | ((unsigned)v[1] << 16);
        o.y = (unsigned)v[2] | ((unsigned)v[3] << 16);
        o.z = (unsigned)v[4] | ((unsigned)v[5] << 16);
        o.w = (unsigned)v[6] | ((unsigned)v[7] << 16);
        wfr[t] = o;
    } else if (t < 80 * 64 + 128) {
        int u = t - 80 * 64;
        const float* b = (u < 64) ? b1 : b2;
        unsigned* dst  = (u < 64) ? b1p : b2p;
        int lane = u & 63, gq = lane >> 4;
        for (int p = 0; p < 16; ++p) {       // pair p covers state elems 2p,2p+1
            int e0 = 2 * p, e1 = 2 * p + 1;
            int ch0 = 16 * (e0 >> 2) + 4 * gq + (e0 & 3);
            int ch1 = 16 * (e1 >> 2) + 4 * gq + (e1 & 3);
            dst[lane * 16 + p] = (unsigned)bf16r(b[ch0]) | ((unsigned)bf16r(b[ch1]) << 16);
        }
    }
}

extern "C" void kernel_launch(void* const* d_in, const int* in_sizes, int n_in,
                              void* d_out, int out_size, void* d_ws, size_t ws_size,
                              hipStream_t stream)
{
    const float* x  = (const float*)d_in[0];
    const float* W1 = (const float*)d_in[1];
    const float* b1 = (const float*)d_in[2];
    const float* W2 = (const float*)d_in[3];
    const float* b2 = (const float*)d_in[4];
    const float* Wl = (const float*)d_in[5];
    const float* bl = (const float*)d_in[6];

    const int n = in_sizes[0] / 128;

    uint4*    wfr = (uint4*)d_ws;                                  // 80*64*16 = 81920 B
    unsigned* b1p = (unsigned*)((char*)d_ws + 81920);              // 4096 B
    unsigned* b2p = (unsigned*)((char*)d_ws + 86016);              // 4096 B

    prep_kernel<<<21, 256, 0, stream>>>(W1, W2, Wl, b1, b2, wfr, b1p, b2p);

    const int nb = (n + 63) / 64;            // 64 rows per block (4 waves x 16)
    gnode_kernel<<<nb, 256, 0, stream>>>(x, wfr, b1p, b2p, bl, (float*)d_out, n);
}

// Round 3
// 682.847 us; speedup vs baseline: 17.4106x; 1.1340x over previous
//
#include <hip/hip_runtime.h>
#include <hip/hip_bf16.h>

// GNODE fully fused: y' = relu(y@W1+b1)@W2+b2, RK4(3/8) x10 steps (h=0.1),
// out = y@Wl+bl.  N=200000 rows, 128 ch, 64 out ch.
//
// Round 3: register-budgeted mega-kernel (round 2 spilled ~550MB scratch).
// - arg / h never materialized in fp32: RK4 combos and relu fused directly
//   into bf16 B-frag construction (matmul rounds to bf16 anyway).
// - __float2bfloat16 casts so compiler emits v_cvt_pk_bf16_f32.
// - Live set: weights 256 + biases(packed bf16) 32 + y/ka/kb/s 128 +
//   frags 16 + inner acc/h ~48  ->  ~488 of 512 unified VGPR/AGPR budget.
// Layout identity (mfma_f32_16x16x32_bf16, HW-verified m89):
//   D:      ch = 16*mb + 4*(lane>>4) + r,              batch = lane&15
//   B-frag: ch = 32*kb + 16*(j>>2) + 4*(lane>>4)+(j&3), batch = lane&15
// => frag[e>>3][e&7] = state[e], e = 4*mb + r.  All lane-local, no LDS.

typedef __attribute__((ext_vector_type(8))) short bf16x8;
typedef __attribute__((ext_vector_type(4))) float f32x4;

constexpr float HS = 0.1f;

__device__ __forceinline__ short bf16s(float f) {
    return (short)__builtin_bit_cast(unsigned short, __float2bfloat16(f));
}
__device__ __forceinline__ float bplo(unsigned u) { return __builtin_bit_cast(float, u << 16); }
__device__ __forceinline__ float bphi(unsigned u) { return __builtin_bit_cast(float, u & 0xffff0000u); }

__device__ __forceinline__ void bias_init(const unsigned (&bp)[16], f32x4 (&acc)[8]) {
    #pragma unroll
    for (int mb = 0; mb < 8; ++mb) {
        acc[mb][0] = bplo(bp[mb * 2 + 0]);
        acc[mb][1] = bphi(bp[mb * 2 + 0]);
        acc[mb][2] = bplo(bp[mb * 2 + 1]);
        acc[mb][3] = bphi(bp[mb * 2 + 1]);
    }
}

__device__ __forceinline__ void mm_core(const bf16x8 (&wf)[32], const bf16x8 (&in)[4],
                                        f32x4 (&acc)[8]) {
    #pragma unroll
    for (int kb = 0; kb < 4; ++kb)          // inner mb: 8 independent accs
        #pragma unroll
        for (int mb = 0; mb < 8; ++mb)
            acc[mb] = __builtin_amdgcn_mfma_f32_16x16x32_bf16(wf[mb * 4 + kb], in[kb], acc[mb], 0, 0, 0);
}

// kout = W2 @ relu(W1 @ in + b1) + b2 ; h kept only as bf16 frags.
__device__ __forceinline__ void feval(const bf16x8 (&w1f)[32], const bf16x8 (&w2f)[32],
                                      const unsigned (&b1p)[16], const unsigned (&b2p)[16],
                                      const bf16x8 (&in)[4], float (&kout)[32])
{
    f32x4 acc[8];
    bias_init(b1p, acc);
    mm_core(w1f, in, acc);
    bf16x8 h[4];
    #pragma unroll
    for (int mb = 0; mb < 8; ++mb)
        #pragma unroll
        for (int r = 0; r < 4; ++r)
            h[mb >> 1][(mb & 1) * 4 + r] = bf16s(fmaxf(acc[mb][r], 0.f));
    f32x4 acc2[8];
    bias_init(b2p, acc2);
    mm_core(w2f, h, acc2);
    #pragma unroll
    for (int mb = 0; mb < 8; ++mb)
        #pragma unroll
        for (int r = 0; r < 4; ++r)
            kout[mb * 4 + r] = acc2[mb][r];
}

__global__ __launch_bounds__(256, 1) void gnode_kernel(
    const float* __restrict__ x, const uint4* __restrict__ wfr,
    const unsigned* __restrict__ b1pg, const unsigned* __restrict__ b2pg,
    const float* __restrict__ bl, float* __restrict__ out, int n)
{
    const int lane = threadIdx.x & 63;
    const int wid  = threadIdx.x >> 6;
    const int g    = lane >> 4;
    const int c16  = lane & 15;
    const int row  = blockIdx.x * 64 + wid * 16 + c16;   // this lane's batch row
    const int rowc = row < n ? row : n - 1;

    bf16x8 w1f[32], w2f[32];
    #pragma unroll
    for (int f = 0; f < 32; ++f) w1f[f] = __builtin_bit_cast(bf16x8, wfr[f * 64 + lane]);
    #pragma unroll
    for (int f = 0; f < 32; ++f) w2f[f] = __builtin_bit_cast(bf16x8, wfr[(32 + f) * 64 + lane]);

    unsigned b1p[16], b2p[16];
    #pragma unroll
    for (int p = 0; p < 16; ++p) b1p[p] = b1pg[lane * 16 + p];
    #pragma unroll
    for (int p = 0; p < 16; ++p) b2p[p] = b2pg[lane * 16 + p];

    // Y^T state, fp32 master: elem e=4*mb+r <-> (ch = 16*mb+4*g+r, batch=row)
    float y[32];
    {
        const f32x4* x4 = (const f32x4*)x;
        #pragma unroll
        for (int cb = 0; cb < 8; ++cb) {
            f32x4 v = x4[(size_t)rowc * 32 + cb * 4 + g];
            y[cb * 4 + 0] = v[0]; y[cb * 4 + 1] = v[1];
            y[cb * 4 + 2] = v[2]; y[cb * 4 + 3] = v[3];
        }
    }

    float ka[32], kb[32], s[32];
    bf16x8 fr[4];

    for (int st = 0; st < 10; ++st) {
        // k1 = f(y)
        #pragma unroll
        for (int e = 0; e < 32; ++e) fr[e >> 3][e & 7] = bf16s(y[e]);
        feval(w1f, w2f, b1p, b2p, fr, ka);
        // k2 = f(y + (h/3) k1)
        #pragma unroll
        for (int e = 0; e < 32; ++e)
            fr[e >> 3][e & 7] = bf16s(fmaf(HS * (1.f / 3.f), ka[e], y[e]));
        feval(w1f, w2f, b1p, b2p, fr, kb);
        // k3 = f(y + h k2 - (h/3) k1)
        #pragma unroll
        for (int e = 0; e < 32; ++e)
            fr[e >> 3][e & 7] = bf16s(fmaf(HS, kb[e], fmaf(-HS * (1.f / 3.f), ka[e], y[e])));
        feval(w1f, w2f, b1p, b2p, fr, s);
        // fold: ka <- k1+3k2+3k3 ; kb <- k1-k2+k3
        #pragma unroll
        for (int e = 0; e < 32; ++e) {
            float u = kb[e];
            kb[e] = ka[e] - u + s[e];
            ka[e] = fmaf(3.f, u + s[e], ka[e]);
        }
        // k4 = f(y + h (k1-k2+k3))
        #pragma unroll
        for (int e = 0; e < 32; ++e) fr[e >> 3][e & 7] = bf16s(fmaf(HS, kb[e], y[e]));
        feval(w1f, w2f, b1p, b2p, fr, s);
        // y += h/8 (ka + k4)
        #pragma unroll
        for (int e = 0; e < 32; ++e) y[e] = fmaf(HS * 0.125f, ka[e] + s[e], y[e]);
    }

    // epilogue: out^T = Wl^T y^T + bl   (64 out ch = 4 mb)
    bf16x8 wlf[16];
    #pragma unroll
    for (int f = 0; f < 16; ++f) wlf[f] = __builtin_bit_cast(bf16x8, wfr[(64 + f) * 64 + lane]);
    bf16x8 yf[4];
    #pragma unroll
    for (int e = 0; e < 32; ++e) yf[e >> 3][e & 7] = bf16s(y[e]);
    f32x4 ao[4];
    {
        const f32x4* bl4 = (const f32x4*)bl;
        #pragma unroll
        for (int mb = 0; mb < 4; ++mb) ao[mb] = bl4[mb * 4 + g];   // bl[16mb+4g+r]
    }
    #pragma unroll
    for (int kv = 0; kv < 4; ++kv)
        #pragma unroll
        for (int mb = 0; mb < 4; ++mb)
            ao[mb] = __builtin_amdgcn_mfma_f32_16x16x32_bf16(wlf[mb * 4 + kv], yf[kv], ao[mb], 0, 0, 0);
    if (row < n) {
        f32x4* out4 = (f32x4*)out;
        #pragma unroll
        for (int mb = 0; mb < 4; ++mb)
            out4[(size_t)row * 16 + mb * 4 + g] = ao[mb];          // out[row][16mb+4g+r]
    }
}

// ---- prep: A-frag-linear bf16 weights + packed-bf16 biases into d_ws ----
// A-frag (16x32): lane l, elem j:  row = l&15 (+16*mb),
//                                  k   = 32*kb + 16*(j>>2) + 4*(l>>4) + (j&3)
// wfr[f*64+lane] : f 0..31 = W1 (mb=f>>2,kb=f&3), 32..63 = W2, 64..79 = Wl.
__global__ void prep_kernel(const float* __restrict__ W1, const float* __restrict__ W2,
                            const float* __restrict__ Wl,
                            const float* __restrict__ b1, const float* __restrict__ b2,
                            uint4* __restrict__ wfr, unsigned* __restrict__ b1p,
                            unsigned* __restrict__ b2p)
{
    int t = blockIdx.x * 256 + threadIdx.x;
    if (t < 80 * 64) {
        int f = t >> 6, lane = t & 63;
        int gq = lane >> 4, c = lane & 15;
        const float* W; int mb, kv, cols;
        if (f < 32)      { W = W1; mb = f >> 2;        kv = f & 3;        cols = 128; }
        else if (f < 64) { W = W2; mb = (f - 32) >> 2; kv = (f - 32) & 3; cols = 128; }
        else             { W = Wl; mb = (f - 64) >> 2; kv = (f - 64) & 3; cols = 64;  }
        int col = mb * 16 + c;               // output-channel (A row)
        unsigned short v[8];
        #pragma unroll
        for (int j = 0; j < 8; ++j) {
            int k = kv * 32 + (j >> 2) * 16 + gq * 4 + (j & 3);
            v[j] = __builtin_bit_cast(unsigned short, __float2bfloat16(W[k * cols + col]));
        }
        uint4 o;
        o.x = (unsigned)v[0] | ((unsigned)v[1] << 16);
        o.y = (unsigned)v[2] | ((unsigned)v[3] << 16);
        o.z = (unsigned)v[4] | ((unsigned)v[5] << 16);
        o.w = (unsigned)v[6] | ((unsigned)v[7] << 16);
        wfr[t] = o;
    } else if (t < 80 * 64 + 128) {
        int u = t - 80 * 64;
        const float* b = (u < 64) ? b1 : b2;
        unsigned* dst  = (u < 64) ? b1p : b2p;
        int lane = u & 63, gq = lane >> 4;
        for (int p = 0; p < 16; ++p) {       // pair p covers state elems 2p,2p+1
            int e0 = 2 * p, e1 = 2 * p + 1;
            int ch0 = 16 * (e0 >> 2) + 4 * gq + (e0 & 3);
            int ch1 = 16 * (e1 >> 2) + 4 * gq + (e1 & 3);
            unsigned short v0 = __builtin_bit_cast(unsigned short, __float2bfloat16(b[ch0]));
            unsigned short v1 = __builtin_bit_cast(unsigned short, __float2bfloat16(b[ch1]));
            dst[lane * 16 + p] = (unsigned)v0 | ((unsigned)v1 << 16);
        }
    }
}

extern "C" void kernel_launch(void* const* d_in, const int* in_sizes, int n_in,
                              void* d_out, int out_size, void* d_ws, size_t ws_size,
                              hipStream_t stream)
{
    const float* x  = (const float*)d_in[0];
    const float* W1 = (const float*)d_in[1];
    const float* b1 = (const float*)d_in[2];
    const float* W2 = (const float*)d_in[3];
    const float* b2 = (const float*)d_in[4];
    const float* Wl = (const float*)d_in[5];
    const float* bl = (const float*)d_in[6];

    const int n = in_sizes[0] / 128;

    uint4*    wfr = (uint4*)d_ws;                                  // 80*64*16 = 81920 B
    unsigned* b1p = (unsigned*)((char*)d_ws + 81920);              // 4096 B
    unsigned* b2p = (unsigned*)((char*)d_ws + 86016);              // 4096 B

    prep_kernel<<<21, 256, 0, stream>>>(W1, W2, Wl, b1, b2, wfr, b1p, b2p);

    const int nb = (n + 63) / 64;            // 64 rows per block (4 waves x 16)
    gnode_kernel<<<nb, 256, 0, stream>>>(x, wfr, b1p, b2p, bl, (float*)d_out, n);
}